// Round 5
// baseline (418.909 us; speedup 1.0000x reference)
//
#include <hip/hip_runtime.h>

#define NHh 16

typedef unsigned short ushortT;
typedef __attribute__((ext_vector_type(8))) short short8;
typedef __attribute__((ext_vector_type(4))) float floatx4;

__device__ __forceinline__ ushortT f2bf(float x) {
    union { float f; unsigned int u; } cv; cv.f = x;
    unsigned int u = cv.u;
    unsigned int r = u + 0x7fffu + ((u >> 16) & 1u);
    return (ushortT)(r >> 16);
}

// truncating pack of two fp32 -> packed bf16x2 (cheap; used for P which is in [0,1])
__device__ __forceinline__ unsigned pack2_trunc(float a, float b) {
    union { float f; unsigned u; } ua, ub;
    ua.f = a; ub.f = b;
    return (ub.u & 0xffff0000u) | (ua.u >> 16);
}

__device__ __forceinline__ void gload_lds16(const ushortT* g, ushortT* l) {
    __builtin_amdgcn_global_load_lds(
        (const __attribute__((address_space(1))) void*)g,
        (__attribute__((address_space(3))) void*)l, 16, 0, 0);
}

// ---------------- fp32 -> bf16 converters ----------------
__global__ __launch_bounds__(256) void cvt_x(const float* __restrict__ in,
                                             ushortT* __restrict__ out, int n4) {
    int i = blockIdx.x * 256 + threadIdx.x;
    if (i >= n4) return;
    float4 f = ((const float4*)in)[i];
    uint2 o;
    o.x = (unsigned)f2bf(f.x) | ((unsigned)f2bf(f.y) << 16);
    o.y = (unsigned)f2bf(f.z) | ((unsigned)f2bf(f.w) << 16);
    ((uint2*)out)[i] = o;
}

__global__ __launch_bounds__(256) void cvt_w(const float* __restrict__ W0, const float* __restrict__ W1,
                                             const float* __restrict__ W2, const float* __restrict__ W3,
                                             ushortT* __restrict__ o0, ushortT* __restrict__ o1,
                                             ushortT* __restrict__ o2, ushortT* __restrict__ o3, int n4) {
    int z = blockIdx.y;
    const float* in = (z == 0) ? W0 : (z == 1) ? W1 : (z == 2) ? W2 : W3;
    ushortT* out = (z == 0) ? o0 : (z == 1) ? o1 : (z == 2) ? o2 : o3;
    int i = blockIdx.x * 256 + threadIdx.x;
    if (i >= n4) return;
    float4 f = ((const float4*)in)[i];
    uint2 o;
    o.x = (unsigned)f2bf(f.x) | ((unsigned)f2bf(f.y) << 16);
    o.y = (unsigned)f2bf(f.z) | ((unsigned)f2bf(f.w) << 16);
    ((uint2*)out)[i] = o;
}

// ---------------- QKV GEMM ----------------
// 1-D grid, 1536 blocks: m = l%64 (XCD = m%8 -> A-tile L2-resident), r=l/64, z=r/8, n=r%8.
// z=0/1 (Q,K): out[token,dim] -> [bh][s][d]; z=2 (V): swapped operands -> V^T [bh][d][s].
__global__ __launch_bounds__(256) void qkv_gemm(const ushortT* __restrict__ X,
        const ushortT* __restrict__ W0, const ushortT* __restrict__ W1, const ushortT* __restrict__ W2,
        const float* __restrict__ b0, const float* __restrict__ b1, const float* __restrict__ b2,
        ushortT* __restrict__ Qo, ushortT* __restrict__ Ko, ushortT* __restrict__ Vo) {
    __shared__ ushortT As[128 * 32];
    __shared__ ushortT Bs[128 * 32];
    const int l = blockIdx.x;
    const int mt = l & 63;
    const int r = l >> 6;
    const int z = r >> 3;
    const int nt = r & 7;
    const int tid = threadIdx.x;
    const int lane = tid & 63;
    const int w = tid >> 6;
    const int qd = lane >> 4;
    const int ln = lane & 15;
    const ushortT* Wt = (z == 0) ? W0 : (z == 1) ? W1 : W2;
    const float* bias = (z == 0) ? b0 : (z == 1) ? b1 : b2;
    const int RM = (w >> 1) * 64;
    const int RN = (w & 1) * 64;

    const ushortT* Ap;
    const ushortT* Bp;
    int arow0, brow0;
    if (z == 2) { Ap = Wt; arow0 = nt * 128; Bp = X;  brow0 = mt * 128; }
    else        { Ap = X;  arow0 = mt * 128; Bp = Wt; brow0 = nt * 128; }

    floatx4 acc[4][4];
#pragma unroll
    for (int i = 0; i < 4; i++)
#pragma unroll
        for (int j = 0; j < 4; j++) acc[i][j] = (floatx4){0.f, 0.f, 0.f, 0.f};

    const int c0 = tid, c1 = tid + 256;
    for (int k0 = 0; k0 < 1024; k0 += 32) {
        gload_lds16(Ap + (size_t)(arow0 + (c0 >> 2)) * 1024 + k0 + (c0 & 3) * 8, As + c0 * 8);
        gload_lds16(Ap + (size_t)(arow0 + (c1 >> 2)) * 1024 + k0 + (c1 & 3) * 8, As + c1 * 8);
        gload_lds16(Bp + (size_t)(brow0 + (c0 >> 2)) * 1024 + k0 + (c0 & 3) * 8, Bs + c0 * 8);
        gload_lds16(Bp + (size_t)(brow0 + (c1 >> 2)) * 1024 + k0 + (c1 & 3) * 8, Bs + c1 * 8);
        __syncthreads();
        short8 af[4], bf8[4];
#pragma unroll
        for (int i = 0; i < 4; i++) af[i] = *(const short8*)&As[(RM + i * 16 + ln) * 32 + qd * 8];
#pragma unroll
        for (int j = 0; j < 4; j++) bf8[j] = *(const short8*)&Bs[(RN + j * 16 + ln) * 32 + qd * 8];
#pragma unroll
        for (int i = 0; i < 4; i++)
#pragma unroll
            for (int j = 0; j < 4; j++)
                acc[i][j] = __builtin_amdgcn_mfma_f32_16x16x32_bf16(af[i], bf8[j], acc[i][j], 0, 0, 0);
        __syncthreads();
    }

    if (z == 2) {
        floatx4 bias4[4];
#pragma unroll
        for (int i = 0; i < 4; i++) bias4[i] = *(const floatx4*)(bias + arow0 + RM + i * 16 + qd * 4);
#pragma unroll
        for (int j = 0; j < 4; j++) {
            int m = brow0 + RN + j * 16 + ln;   // token
            int bb = m >> 10, s = m & 1023;
#pragma unroll
            for (int i = 0; i < 4; i++) {
#pragma unroll
                for (int r2 = 0; r2 < 4; r2++) {
                    int a = arow0 + RM + i * 16 + qd * 4 + r2;  // dim
                    int hh = a >> 6, dd = a & 63;
                    float v = acc[i][j][r2] + bias4[i][r2];
                    Vo[((size_t)(bb * NHh + hh) * 64 + dd) * 1024 + s] = f2bf(v);
                }
            }
        }
    } else {
        ushortT* Out = (z == 0) ? Qo : Ko;
#pragma unroll
        for (int j = 0; j < 4; j++) {
            int n = brow0 + RN + j * 16 + ln;   // dim
            float bb = bias[n];
            int h = n >> 6, d = n & 63;
#pragma unroll
            for (int i = 0; i < 4; i++) {
#pragma unroll
                for (int r2 = 0; r2 < 4; r2++) {
                    int m = arow0 + RM + i * 16 + qd * 4 + r2;  // token
                    int b = m >> 10, s = m & 1023;
                    float v = acc[i][j][r2] + bb;
                    Out[(size_t)((b * NHh + h) * 1024 + s) * 64 + d] = f2bf(v);
                }
            }
        }
    }
}

// ---------------- out-proj GEMM (fp32 out), 1-D grid 512: m=l%64, n=l/64 ----------------
__global__ __launch_bounds__(256) void oproj_gemm(const ushortT* __restrict__ A,
        const ushortT* __restrict__ Wt, const float* __restrict__ bias, float* __restrict__ Pj) {
    __shared__ ushortT As[128 * 32];
    __shared__ ushortT Bs[128 * 32];
    const int l = blockIdx.x;
    const int m0 = (l & 63) * 128;
    const int n0 = (l >> 6) * 128;
    const int tid = threadIdx.x;
    const int lane = tid & 63;
    const int w = tid >> 6;
    const int qd = lane >> 4;
    const int ln = lane & 15;
    const int RM = (w >> 1) * 64;
    const int RN = (w & 1) * 64;

    floatx4 acc[4][4];
#pragma unroll
    for (int i = 0; i < 4; i++)
#pragma unroll
        for (int j = 0; j < 4; j++) acc[i][j] = (floatx4){0.f, 0.f, 0.f, 0.f};

    const int c0 = tid, c1 = tid + 256;
    for (int k0 = 0; k0 < 1024; k0 += 32) {
        gload_lds16(A + (size_t)(m0 + (c0 >> 2)) * 1024 + k0 + (c0 & 3) * 8, As + c0 * 8);
        gload_lds16(A + (size_t)(m0 + (c1 >> 2)) * 1024 + k0 + (c1 & 3) * 8, As + c1 * 8);
        gload_lds16(Wt + (size_t)(n0 + (c0 >> 2)) * 1024 + k0 + (c0 & 3) * 8, Bs + c0 * 8);
        gload_lds16(Wt + (size_t)(n0 + (c1 >> 2)) * 1024 + k0 + (c1 & 3) * 8, Bs + c1 * 8);
        __syncthreads();
        short8 af[4], bf8[4];
#pragma unroll
        for (int i = 0; i < 4; i++) af[i] = *(const short8*)&As[(RM + i * 16 + ln) * 32 + qd * 8];
#pragma unroll
        for (int j = 0; j < 4; j++) bf8[j] = *(const short8*)&Bs[(RN + j * 16 + ln) * 32 + qd * 8];
#pragma unroll
        for (int i = 0; i < 4; i++)
#pragma unroll
            for (int j = 0; j < 4; j++)
                acc[i][j] = __builtin_amdgcn_mfma_f32_16x16x32_bf16(af[i], bf8[j], acc[i][j], 0, 0, 0);
        __syncthreads();
    }

#pragma unroll
    for (int j = 0; j < 4; j++) {
        int n = n0 + RN + j * 16 + ln;
        float bb = bias[n];
#pragma unroll
        for (int i = 0; i < 4; i++) {
#pragma unroll
            for (int r2 = 0; r2 < 4; r2++) {
                int m = m0 + RM + i * 16 + qd * 4 + r2;
                Pj[(size_t)m * 1024 + n] = acc[i][j][r2] + bb;
            }
        }
    }
}

// ---------------- flash attention: barrier-free, all-global fragments ----------------
// 1-D grid 1024: bh = l%128 (XCD = bh%8 -> K/V L2-resident), qb = l/128.
// S^T = K·Q^T (A=K from L2, B=Q registers). P -> per-wave LDS (A-layout).
// PV: A=P (LDS), B=V^T straight from L2 ([bh][d][s] IS the B-fragment layout).
// No Vt staging, no __syncthreads anywhere: LDS = 18 KB, 4 blocks/CU, grid fully resident.
__global__ __launch_bounds__(256, 4) void attn_kernel(const ushortT* __restrict__ Q,
        const ushortT* __restrict__ K, const ushortT* __restrict__ Vg_t,
        const float* __restrict__ mask, ushortT* __restrict__ ctx) {
    __shared__ __align__(16) ushortT Ps[4][32 * 72];    // 18 KB, per-wave [32 q][64 s + pad]

    const int tid = threadIdx.x;
    const int lane = tid & 63;
    const int w = tid >> 6;
    const int qd = lane >> 4;
    const int ln = lane & 15;
    const int l = blockIdx.x;
    const int bh = l & 127;
    const int b = bh >> 4;
    const int h = bh & 15;
    const int qb = l >> 7;

    const ushortT* Qg = Q + (size_t)bh * 65536;
    const ushortT* Kg = K + (size_t)bh * 65536;
    const ushortT* Vg = Vg_t + (size_t)bh * 65536;
    const float* mrow = mask + b * 1024;
    const float LOG2E = 1.4426950408889634f;
    const float SCL = 0.125f * 1.4426950408889634f;   // fold 1/sqrt(64) and log2e

    // resident Q B-fragments
    short8 qf[2][2];
#pragma unroll
    for (int nj = 0; nj < 2; nj++)
#pragma unroll
        for (int ks = 0; ks < 2; ks++)
            qf[nj][ks] = *(const short8*)(Qg + (size_t)(qb * 128 + w * 32 + nj * 16 + ln) * 64 + ks * 32 + qd * 8);

    float lst[2] = {0.f, 0.f};
    floatx4 accO[2][4];
#pragma unroll
    for (int i = 0; i < 2; i++)
#pragma unroll
        for (int j = 0; j < 4; j++) accO[i][j] = (floatx4){0.f, 0.f, 0.f, 0.f};

    for (int kt = 0; kt < 8; ++kt) {
#pragma unroll
        for (int h2 = 0; h2 < 2; ++h2) {
            const int s0 = kt * 128 + h2 * 64;

            // ---- S^T: A = K rows s0..s0+63 (global/L2), B = Q (regs) ----
            floatx4 sv[4][2];
#pragma unroll
            for (int mi = 0; mi < 4; mi++)
#pragma unroll
                for (int nj = 0; nj < 2; nj++) sv[mi][nj] = (floatx4){0.f, 0.f, 0.f, 0.f};
#pragma unroll
            for (int ks = 0; ks < 2; ks++) {
                short8 af[4];
#pragma unroll
                for (int mi = 0; mi < 4; mi++)
                    af[mi] = *(const short8*)(Kg + (size_t)(s0 + mi * 16 + ln) * 64 + ks * 32 + qd * 8);
#pragma unroll
                for (int mi = 0; mi < 4; mi++)
#pragma unroll
                    for (int nj = 0; nj < 2; nj++)
                        sv[mi][nj] = __builtin_amdgcn_mfma_f32_16x16x32_bf16(af[mi], qf[nj][ks], sv[mi][nj], 0, 0, 0);
            }

            // ---- softmax-lite (static max) + per-wave Ps write (truncation pack) ----
            {
                float rs0 = 0.f, rs1 = 0.f;
#pragma unroll
                for (int mi = 0; mi < 4; mi++) {
                    floatx4 m4 = *(const floatx4*)(mrow + s0 + mi * 16 + qd * 4);
                    float p00 = __builtin_amdgcn_exp2f(sv[mi][0][0] * SCL + m4[0] * LOG2E);
                    float p01 = __builtin_amdgcn_exp2f(sv[mi][0][1] * SCL + m4[1] * LOG2E);
                    float p02 = __builtin_amdgcn_exp2f(sv[mi][0][2] * SCL + m4[2] * LOG2E);
                    float p03 = __builtin_amdgcn_exp2f(sv[mi][0][3] * SCL + m4[3] * LOG2E);
                    float p10 = __builtin_amdgcn_exp2f(sv[mi][1][0] * SCL + m4[0] * LOG2E);
                    float p11 = __builtin_amdgcn_exp2f(sv[mi][1][1] * SCL + m4[1] * LOG2E);
                    float p12 = __builtin_amdgcn_exp2f(sv[mi][1][2] * SCL + m4[2] * LOG2E);
                    float p13 = __builtin_amdgcn_exp2f(sv[mi][1][3] * SCL + m4[3] * LOG2E);
                    rs0 += (p00 + p01) + (p02 + p03);
                    rs1 += (p10 + p11) + (p12 + p13);
                    uint2 w0, w1;
                    w0.x = pack2_trunc(p00, p01); w0.y = pack2_trunc(p02, p03);
                    w1.x = pack2_trunc(p10, p11); w1.y = pack2_trunc(p12, p13);
                    *(uint2*)&Ps[w][(0 * 16 + ln) * 72 + mi * 16 + qd * 4] = w0;
                    *(uint2*)&Ps[w][(1 * 16 + ln) * 72 + mi * 16 + qd * 4] = w1;
                }
                rs0 += __shfl_xor(rs0, 16, 64); rs0 += __shfl_xor(rs0, 32, 64);
                rs1 += __shfl_xor(rs1, 16, 64); rs1 += __shfl_xor(rs1, 32, 64);
                lst[0] += rs0; lst[1] += rs1;
            }

            // ---- PV: A = P (per-wave LDS), B = V^T rows d (global/L2) ----
#pragma unroll
            for (int ks2 = 0; ks2 < 2; ks2++) {
                short8 ap[2], bv[4];
#pragma unroll
                for (int i = 0; i < 2; i++)
                    ap[i] = *(const short8*)&Ps[w][(i * 16 + ln) * 72 + ks2 * 32 + qd * 8];
#pragma unroll
                for (int j = 0; j < 4; j++)
                    bv[j] = *(const short8*)(Vg + (size_t)(j * 16 + ln) * 1024 + s0 + ks2 * 32 + qd * 8);
#pragma unroll
                for (int i = 0; i < 2; i++)
#pragma unroll
                    for (int j = 0; j < 4; j++)
                        accO[i][j] = __builtin_amdgcn_mfma_f32_16x16x32_bf16(ap[i], bv[j], accO[i][j], 0, 0, 0);
            }
        }
    }

    // epilogue: divide by l (lane transpose once) and store ctx [b][s=q][h*64+d]
#pragma unroll
    for (int i = 0; i < 2; i++) {
#pragma unroll
        for (int r = 0; r < 4; r++) {
            float lv = __shfl(lst[i], qd * 4 + r, 64);
            float linv = 1.f / lv;
            int q = qb * 128 + w * 32 + i * 16 + qd * 4 + r;
#pragma unroll
            for (int j = 0; j < 4; j++) {
                int d = j * 16 + ln;
                ctx[((size_t)(b * 1024 + q)) * 1024 + h * 64 + d] = f2bf(accO[i][j][r] * linv);
            }
        }
    }
}

// ---------------- residual + LayerNorm ----------------
__global__ __launch_bounds__(256) void ln_kernel(const float* __restrict__ Pj, const float* __restrict__ X,
        const float* __restrict__ gamma, const float* __restrict__ beta, float* __restrict__ out) {
    __shared__ float red[8];
    int row = blockIdx.x;
    int t = threadIdx.x;
    const float4 p4 = ((const float4*)(Pj + (size_t)row * 1024))[t];
    const float4 x4 = ((const float4*)(X + (size_t)row * 1024))[t];
    float r0 = p4.x + x4.x, r1 = p4.y + x4.y, r2 = p4.z + x4.z, r3 = p4.w + x4.w;
    float s = r0 + r1 + r2 + r3;
    float ss = r0 * r0 + r1 * r1 + r2 * r2 + r3 * r3;
#pragma unroll
    for (int o = 1; o < 64; o <<= 1) { s += __shfl_xor(s, o, 64); ss += __shfl_xor(ss, o, 64); }
    int w = t >> 6;
    if ((t & 63) == 0) { red[w] = s; red[4 + w] = ss; }
    __syncthreads();
    s = red[0] + red[1] + red[2] + red[3];
    ss = red[4] + red[5] + red[6] + red[7];
    float mu = s * (1.f / 1024.f);
    float var = ss * (1.f / 1024.f) - mu * mu;
    float inv = rsqrtf(var + 1e-12f);
    const float4 g4 = ((const float4*)gamma)[t];
    const float4 b4 = ((const float4*)beta)[t];
    float4 o4;
    o4.x = (r0 - mu) * inv * g4.x + b4.x;
    o4.y = (r1 - mu) * inv * g4.y + b4.y;
    o4.z = (r2 - mu) * inv * g4.z + b4.z;
    o4.w = (r3 - mu) * inv * g4.w + b4.w;
    ((float4*)(out + (size_t)row * 1024))[t] = o4;
}

extern "C" void kernel_launch(void* const* d_in, const int* in_sizes, int n_in,
                              void* d_out, int out_size, void* d_ws, size_t ws_size,
                              hipStream_t stream) {
    const float* x     = (const float*)d_in[0];
    const float* mask  = (const float*)d_in[1];
    const float* Wq    = (const float*)d_in[2];
    const float* bq    = (const float*)d_in[3];
    const float* Wk    = (const float*)d_in[4];
    const float* bk    = (const float*)d_in[5];
    const float* Wv    = (const float*)d_in[6];
    const float* bv    = (const float*)d_in[7];
    const float* Wo    = (const float*)d_in[8];
    const float* bo    = (const float*)d_in[9];
    const float* gamma = (const float*)d_in[10];
    const float* beta  = (const float*)d_in[11];
    float* out = (float*)d_out;

    char* ws = (char*)d_ws;
    ushortT* Xb  = (ushortT*)(ws);
    ushortT* Wqb = (ushortT*)(ws + (16u << 20));
    ushortT* Wkb = (ushortT*)(ws + (18u << 20));
    ushortT* Wvb = (ushortT*)(ws + (20u << 20));
    ushortT* Wob = (ushortT*)(ws + (22u << 20));
    ushortT* Qb  = (ushortT*)(ws + (24u << 20));
    ushortT* Kb  = (ushortT*)(ws + (40u << 20));
    ushortT* Vb  = (ushortT*)(ws + (56u << 20));  // V^T [bh][d][s]
    ushortT* Cb  = (ushortT*)(ws);                // ctx reuses Xb
    float*   Pj  = (float*)(ws + (24u << 20));    // fp32 proj reuses Q/K

    cvt_x<<<8192, 256, 0, stream>>>(x, Xb, 2097152);
    cvt_w<<<dim3(1024, 4), 256, 0, stream>>>(Wq, Wk, Wv, Wo, Wqb, Wkb, Wvb, Wob, 262144);
    qkv_gemm<<<1536, 256, 0, stream>>>(Xb, Wqb, Wkb, Wvb, bq, bk, bv, Qb, Kb, Vb);
    attn_kernel<<<1024, 256, 0, stream>>>(Qb, Kb, Vb, mask, Cb);
    oproj_gemm<<<512, 256, 0, stream>>>(Cb, Wob, bo, Pj);
    ln_kernel<<<8192, 256, 0, stream>>>(Pj, x, gamma, beta, out);
}

// Round 6
// 320.888 us; speedup vs baseline: 1.3055x; 1.3055x over previous
//
#include <hip/hip_runtime.h>

#define NHh 16

typedef unsigned short ushortT;
typedef __attribute__((ext_vector_type(8))) short short8;
typedef __attribute__((ext_vector_type(4))) float floatx4;

__device__ __forceinline__ ushortT f2bf(float x) {
    union { float f; unsigned int u; } cv; cv.f = x;
    unsigned int u = cv.u;
    unsigned int r = u + 0x7fffu + ((u >> 16) & 1u);
    return (ushortT)(r >> 16);
}

// truncating pack of two fp32 -> packed bf16x2 (cheap; used for P which is in [0,1])
__device__ __forceinline__ unsigned pack2_trunc(float a, float b) {
    union { float f; unsigned u; } ua, ub;
    ua.f = a; ub.f = b;
    return (ub.u & 0xffff0000u) | (ua.u >> 16);
}

__device__ __forceinline__ void gload_lds16(const ushortT* g, ushortT* l) {
    __builtin_amdgcn_global_load_lds(
        (const __attribute__((address_space(1))) void*)g,
        (__attribute__((address_space(3))) void*)l, 16, 0, 0);
}

// ---------------- fp32 -> bf16 converters ----------------
__global__ __launch_bounds__(256) void cvt_x(const float* __restrict__ in,
                                             ushortT* __restrict__ out, int n4) {
    int i = blockIdx.x * 256 + threadIdx.x;
    if (i >= n4) return;
    float4 f = ((const float4*)in)[i];
    uint2 o;
    o.x = (unsigned)f2bf(f.x) | ((unsigned)f2bf(f.y) << 16);
    o.y = (unsigned)f2bf(f.z) | ((unsigned)f2bf(f.w) << 16);
    ((uint2*)out)[i] = o;
}

__global__ __launch_bounds__(256) void cvt_w(const float* __restrict__ W0, const float* __restrict__ W1,
                                             const float* __restrict__ W2, const float* __restrict__ W3,
                                             ushortT* __restrict__ o0, ushortT* __restrict__ o1,
                                             ushortT* __restrict__ o2, ushortT* __restrict__ o3, int n4) {
    int z = blockIdx.y;
    const float* in = (z == 0) ? W0 : (z == 1) ? W1 : (z == 2) ? W2 : W3;
    ushortT* out = (z == 0) ? o0 : (z == 1) ? o1 : (z == 2) ? o2 : o3;
    int i = blockIdx.x * 256 + threadIdx.x;
    if (i >= n4) return;
    float4 f = ((const float4*)in)[i];
    uint2 o;
    o.x = (unsigned)f2bf(f.x) | ((unsigned)f2bf(f.y) << 16);
    o.y = (unsigned)f2bf(f.z) | ((unsigned)f2bf(f.w) << 16);
    ((uint2*)out)[i] = o;
}

// ---------------- QKV GEMM ----------------
// 1-D grid, 1536 blocks: m = l%64 (XCD = m%8 -> A-tile L2-resident), r=l/64, z=r/8, n=r%8.
// z=0/1 (Q,K): out[token,dim] -> [bh][s][d]; z=2 (V): swapped operands -> V^T [bh][d][s].
__global__ __launch_bounds__(256) void qkv_gemm(const ushortT* __restrict__ X,
        const ushortT* __restrict__ W0, const ushortT* __restrict__ W1, const ushortT* __restrict__ W2,
        const float* __restrict__ b0, const float* __restrict__ b1, const float* __restrict__ b2,
        ushortT* __restrict__ Qo, ushortT* __restrict__ Ko, ushortT* __restrict__ Vo) {
    __shared__ ushortT As[128 * 32];
    __shared__ ushortT Bs[128 * 32];
    const int l = blockIdx.x;
    const int mt = l & 63;
    const int r = l >> 6;
    const int z = r >> 3;
    const int nt = r & 7;
    const int tid = threadIdx.x;
    const int lane = tid & 63;
    const int w = tid >> 6;
    const int qd = lane >> 4;
    const int ln = lane & 15;
    const ushortT* Wt = (z == 0) ? W0 : (z == 1) ? W1 : W2;
    const float* bias = (z == 0) ? b0 : (z == 1) ? b1 : b2;
    const int RM = (w >> 1) * 64;
    const int RN = (w & 1) * 64;

    const ushortT* Ap;
    const ushortT* Bp;
    int arow0, brow0;
    if (z == 2) { Ap = Wt; arow0 = nt * 128; Bp = X;  brow0 = mt * 128; }
    else        { Ap = X;  arow0 = mt * 128; Bp = Wt; brow0 = nt * 128; }

    floatx4 acc[4][4];
#pragma unroll
    for (int i = 0; i < 4; i++)
#pragma unroll
        for (int j = 0; j < 4; j++) acc[i][j] = (floatx4){0.f, 0.f, 0.f, 0.f};

    const int c0 = tid, c1 = tid + 256;
    for (int k0 = 0; k0 < 1024; k0 += 32) {
        gload_lds16(Ap + (size_t)(arow0 + (c0 >> 2)) * 1024 + k0 + (c0 & 3) * 8, As + c0 * 8);
        gload_lds16(Ap + (size_t)(arow0 + (c1 >> 2)) * 1024 + k0 + (c1 & 3) * 8, As + c1 * 8);
        gload_lds16(Bp + (size_t)(brow0 + (c0 >> 2)) * 1024 + k0 + (c0 & 3) * 8, Bs + c0 * 8);
        gload_lds16(Bp + (size_t)(brow0 + (c1 >> 2)) * 1024 + k0 + (c1 & 3) * 8, Bs + c1 * 8);
        __syncthreads();
        short8 af[4], bf8[4];
#pragma unroll
        for (int i = 0; i < 4; i++) af[i] = *(const short8*)&As[(RM + i * 16 + ln) * 32 + qd * 8];
#pragma unroll
        for (int j = 0; j < 4; j++) bf8[j] = *(const short8*)&Bs[(RN + j * 16 + ln) * 32 + qd * 8];
#pragma unroll
        for (int i = 0; i < 4; i++)
#pragma unroll
            for (int j = 0; j < 4; j++)
                acc[i][j] = __builtin_amdgcn_mfma_f32_16x16x32_bf16(af[i], bf8[j], acc[i][j], 0, 0, 0);
        __syncthreads();
    }

    if (z == 2) {
        floatx4 bias4[4];
#pragma unroll
        for (int i = 0; i < 4; i++) bias4[i] = *(const floatx4*)(bias + arow0 + RM + i * 16 + qd * 4);
#pragma unroll
        for (int j = 0; j < 4; j++) {
            int m = brow0 + RN + j * 16 + ln;   // token
            int bb = m >> 10, s = m & 1023;
#pragma unroll
            for (int i = 0; i < 4; i++) {
#pragma unroll
                for (int r2 = 0; r2 < 4; r2++) {
                    int a = arow0 + RM + i * 16 + qd * 4 + r2;  // dim
                    int hh = a >> 6, dd = a & 63;
                    float v = acc[i][j][r2] + bias4[i][r2];
                    Vo[((size_t)(bb * NHh + hh) * 64 + dd) * 1024 + s] = f2bf(v);
                }
            }
        }
    } else {
        ushortT* Out = (z == 0) ? Qo : Ko;
#pragma unroll
        for (int j = 0; j < 4; j++) {
            int n = brow0 + RN + j * 16 + ln;   // dim
            float bb = bias[n];
            int h = n >> 6, d = n & 63;
#pragma unroll
            for (int i = 0; i < 4; i++) {
#pragma unroll
                for (int r2 = 0; r2 < 4; r2++) {
                    int m = arow0 + RM + i * 16 + qd * 4 + r2;  // token
                    int b = m >> 10, s = m & 1023;
                    float v = acc[i][j][r2] + bb;
                    Out[(size_t)((b * NHh + h) * 1024 + s) * 64 + d] = f2bf(v);
                }
            }
        }
    }
}

// ---------------- out-proj GEMM (fp32 out), 1-D grid 512: m=l%64, n=l/64 ----------------
__global__ __launch_bounds__(256) void oproj_gemm(const ushortT* __restrict__ A,
        const ushortT* __restrict__ Wt, const float* __restrict__ bias, float* __restrict__ Pj) {
    __shared__ ushortT As[128 * 32];
    __shared__ ushortT Bs[128 * 32];
    const int l = blockIdx.x;
    const int m0 = (l & 63) * 128;
    const int n0 = (l >> 6) * 128;
    const int tid = threadIdx.x;
    const int lane = tid & 63;
    const int w = tid >> 6;
    const int qd = lane >> 4;
    const int ln = lane & 15;
    const int RM = (w >> 1) * 64;
    const int RN = (w & 1) * 64;

    floatx4 acc[4][4];
#pragma unroll
    for (int i = 0; i < 4; i++)
#pragma unroll
        for (int j = 0; j < 4; j++) acc[i][j] = (floatx4){0.f, 0.f, 0.f, 0.f};

    const int c0 = tid, c1 = tid + 256;
    for (int k0 = 0; k0 < 1024; k0 += 32) {
        gload_lds16(A + (size_t)(m0 + (c0 >> 2)) * 1024 + k0 + (c0 & 3) * 8, As + c0 * 8);
        gload_lds16(A + (size_t)(m0 + (c1 >> 2)) * 1024 + k0 + (c1 & 3) * 8, As + c1 * 8);
        gload_lds16(Wt + (size_t)(n0 + (c0 >> 2)) * 1024 + k0 + (c0 & 3) * 8, Bs + c0 * 8);
        gload_lds16(Wt + (size_t)(n0 + (c1 >> 2)) * 1024 + k0 + (c1 & 3) * 8, Bs + c1 * 8);
        __syncthreads();
        short8 af[4], bf8[4];
#pragma unroll
        for (int i = 0; i < 4; i++) af[i] = *(const short8*)&As[(RM + i * 16 + ln) * 32 + qd * 8];
#pragma unroll
        for (int j = 0; j < 4; j++) bf8[j] = *(const short8*)&Bs[(RN + j * 16 + ln) * 32 + qd * 8];
#pragma unroll
        for (int i = 0; i < 4; i++)
#pragma unroll
            for (int j = 0; j < 4; j++)
                acc[i][j] = __builtin_amdgcn_mfma_f32_16x16x32_bf16(af[i], bf8[j], acc[i][j], 0, 0, 0);
        __syncthreads();
    }

#pragma unroll
    for (int j = 0; j < 4; j++) {
        int n = n0 + RN + j * 16 + ln;
        float bb = bias[n];
#pragma unroll
        for (int i = 0; i < 4; i++) {
#pragma unroll
            for (int r2 = 0; r2 < 4; r2++) {
                int m = m0 + RM + i * 16 + qd * 4 + r2;
                Pj[(size_t)m * 1024 + n] = acc[i][j][r2] + bb;
            }
        }
    }
}

// ---------------- flash attention: LDS-staged K and V^T (coalesced, XOR-swizzled) ----------------
// 1-D grid 1024: bh = l%128 (XCD = bh%8 -> K/V L2-resident), qb = l/128.
// Theory: direct-from-L2 MFMA fragments scatter 16 cache lines per load; staging through
// LDS with contiguous 1KB gload_lds makes L2 traffic coalesced and fragment reads b128.
// K tile [128 s][64 d], 8 chunks/row, chunk g stored at slot g^(s&7).
// V^T tile [64 d][128 s], 16 chunks/row, chunk g stored at slot g^(d&15).
// Ps per-wave. Two barriers per kt (m97 pattern).
__global__ __launch_bounds__(256, 3) void attn_kernel(const ushortT* __restrict__ Q,
        const ushortT* __restrict__ K, const ushortT* __restrict__ Vg_t,
        const float* __restrict__ mask, ushortT* __restrict__ ctx) {
    __shared__ __align__(16) ushortT Ks[128 * 64];      // 16 KB
    __shared__ __align__(16) ushortT Vt[64 * 128];      // 16 KB
    __shared__ __align__(16) ushortT Ps[4][32 * 72];    // 18 KB, per-wave [32 q][64 s + pad]

    const int tid = threadIdx.x;
    const int lane = tid & 63;
    const int w = tid >> 6;
    const int qd = lane >> 4;
    const int ln = lane & 15;
    const int l = blockIdx.x;
    const int bh = l & 127;
    const int b = bh >> 4;
    const int h = bh & 15;
    const int qb = l >> 7;

    const ushortT* Qg = Q + (size_t)bh * 65536;
    const ushortT* Kg = K + (size_t)bh * 65536;
    const ushortT* Vg = Vg_t + (size_t)bh * 65536;
    const float* mrow = mask + b * 1024;
    const float LOG2E = 1.4426950408889634f;
    const float SCL = 0.125f * 1.4426950408889634f;   // fold 1/sqrt(64) and log2e

    // resident Q B-fragments
    short8 qf[2][2];
#pragma unroll
    for (int nj = 0; nj < 2; nj++)
#pragma unroll
        for (int ks = 0; ks < 2; ks++)
            qf[nj][ks] = *(const short8*)(Qg + (size_t)(qb * 128 + w * 32 + nj * 16 + ln) * 64 + ks * 32 + qd * 8);

    float lst[2] = {0.f, 0.f};
    floatx4 accO[2][4];
#pragma unroll
    for (int i = 0; i < 2; i++)
#pragma unroll
        for (int j = 0; j < 4; j++) accO[i][j] = (floatx4){0.f, 0.f, 0.f, 0.f};

    // staging lane geometry
    const int ksr = lane >> 3;          // K: s-subrow within 8-row group
    const int kc  = lane & 7;           // K: chunk index (8 x 16B per 128B row)
    const int vdr = lane >> 4;          // V: d-subrow within 4-row group
    const int vcc = lane & 15;          // V: chunk index (16 x 16B per 256B row)

    for (int kt = 0; kt < 8; ++kt) {
        __syncthreads();   // all waves done reading Ks/Vt of kt-1

        // stage K tile: rows kt*128..+127, swizzled source chunk (self-inverse XOR)
#pragma unroll
        for (int ii = 0; ii < 4; ii++) {
            int i = w * 4 + ii;                 // 16 insts of 8 rows
            int srow = i * 8 + ksr;
            gload_lds16(Kg + (size_t)(kt * 128 + srow) * 64 + (kc ^ ksr) * 8,
                        Ks + i * 512 + lane * 8);
        }
        // stage V^T tile: rows d 0..63, cols kt*128..+127
#pragma unroll
        for (int ii = 0; ii < 4; ii++) {
            int i = w * 4 + ii;                 // 16 insts of 4 rows
            int d = i * 4 + vdr;
            gload_lds16(Vg + (size_t)d * 1024 + kt * 128 + (vcc ^ (d & 15)) * 8,
                        Vt + i * 512 + lane * 8);
        }

        __syncthreads();   // tiles ready (compiler drains vmcnt before barrier)

#pragma unroll
        for (int h2 = 0; h2 < 2; ++h2) {
            const int s0g = kt * 128 + h2 * 64;

            // ---- S^T: A = K rows (LDS, swizzled), B = Q (regs) ----
            floatx4 sv[4][2];
#pragma unroll
            for (int mi = 0; mi < 4; mi++)
#pragma unroll
                for (int nj = 0; nj < 2; nj++) sv[mi][nj] = (floatx4){0.f, 0.f, 0.f, 0.f};
#pragma unroll
            for (int ks = 0; ks < 2; ks++) {
                short8 af[4];
#pragma unroll
                for (int mi = 0; mi < 4; mi++)
                    af[mi] = *(const short8*)&Ks[(h2 * 64 + mi * 16 + ln) * 64 +
                                                 (((ks * 4 + qd) ^ (ln & 7)) * 8)];
#pragma unroll
                for (int mi = 0; mi < 4; mi++)
#pragma unroll
                    for (int nj = 0; nj < 2; nj++)
                        sv[mi][nj] = __builtin_amdgcn_mfma_f32_16x16x32_bf16(af[mi], qf[nj][ks], sv[mi][nj], 0, 0, 0);
            }

            // ---- softmax-lite (static max) + per-wave Ps write ----
            {
                float rs0 = 0.f, rs1 = 0.f;
#pragma unroll
                for (int mi = 0; mi < 4; mi++) {
                    floatx4 m4 = *(const floatx4*)(mrow + s0g + mi * 16 + qd * 4);
                    float p00 = __builtin_amdgcn_exp2f(sv[mi][0][0] * SCL + m4[0] * LOG2E);
                    float p01 = __builtin_amdgcn_exp2f(sv[mi][0][1] * SCL + m4[1] * LOG2E);
                    float p02 = __builtin_amdgcn_exp2f(sv[mi][0][2] * SCL + m4[2] * LOG2E);
                    float p03 = __builtin_amdgcn_exp2f(sv[mi][0][3] * SCL + m4[3] * LOG2E);
                    float p10 = __builtin_amdgcn_exp2f(sv[mi][1][0] * SCL + m4[0] * LOG2E);
                    float p11 = __builtin_amdgcn_exp2f(sv[mi][1][1] * SCL + m4[1] * LOG2E);
                    float p12 = __builtin_amdgcn_exp2f(sv[mi][1][2] * SCL + m4[2] * LOG2E);
                    float p13 = __builtin_amdgcn_exp2f(sv[mi][1][3] * SCL + m4[3] * LOG2E);
                    rs0 += (p00 + p01) + (p02 + p03);
                    rs1 += (p10 + p11) + (p12 + p13);
                    uint2 w0, w1;
                    w0.x = pack2_trunc(p00, p01); w0.y = pack2_trunc(p02, p03);
                    w1.x = pack2_trunc(p10, p11); w1.y = pack2_trunc(p12, p13);
                    *(uint2*)&Ps[w][(0 * 16 + ln) * 72 + mi * 16 + qd * 4] = w0;
                    *(uint2*)&Ps[w][(1 * 16 + ln) * 72 + mi * 16 + qd * 4] = w1;
                }
                rs0 += __shfl_xor(rs0, 16, 64); rs0 += __shfl_xor(rs0, 32, 64);
                rs1 += __shfl_xor(rs1, 16, 64); rs1 += __shfl_xor(rs1, 32, 64);
                lst[0] += rs0; lst[1] += rs1;
            }

            // ---- PV: A = P (per-wave LDS), B = V^T rows (LDS, swizzled) ----
#pragma unroll
            for (int ks2 = 0; ks2 < 2; ks2++) {
                short8 ap[2], bv[4];
#pragma unroll
                for (int i = 0; i < 2; i++)
                    ap[i] = *(const short8*)&Ps[w][(i * 16 + ln) * 72 + ks2 * 32 + qd * 8];
#pragma unroll
                for (int j = 0; j < 4; j++)
                    bv[j] = *(const short8*)&Vt[(j * 16 + ln) * 128 +
                                                (((h2 * 8 + ks2 * 4 + qd) ^ ln) * 8)];
#pragma unroll
                for (int i = 0; i < 2; i++)
#pragma unroll
                    for (int j = 0; j < 4; j++)
                        accO[i][j] = __builtin_amdgcn_mfma_f32_16x16x32_bf16(ap[i], bv[j], accO[i][j], 0, 0, 0);
            }
        }
    }

    // epilogue: divide by l (lane transpose once) and store ctx [b][s=q][h*64+d]
#pragma unroll
    for (int i = 0; i < 2; i++) {
#pragma unroll
        for (int r = 0; r < 4; r++) {
            float lv = __shfl(lst[i], qd * 4 + r, 64);
            float linv = 1.f / lv;
            int q = qb * 128 + w * 32 + i * 16 + qd * 4 + r;
#pragma unroll
            for (int j = 0; j < 4; j++) {
                int d = j * 16 + ln;
                ctx[((size_t)(b * 1024 + q)) * 1024 + h * 64 + d] = f2bf(accO[i][j][r] * linv);
            }
        }
    }
}

// ---------------- residual + LayerNorm ----------------
__global__ __launch_bounds__(256) void ln_kernel(const float* __restrict__ Pj, const float* __restrict__ X,
        const float* __restrict__ gamma, const float* __restrict__ beta, float* __restrict__ out) {
    __shared__ float red[8];
    int row = blockIdx.x;
    int t = threadIdx.x;
    const float4 p4 = ((const float4*)(Pj + (size_t)row * 1024))[t];
    const float4 x4 = ((const float4*)(X + (size_t)row * 1024))[t];
    float r0 = p4.x + x4.x, r1 = p4.y + x4.y, r2 = p4.z + x4.z, r3 = p4.w + x4.w;
    float s = r0 + r1 + r2 + r3;
    float ss = r0 * r0 + r1 * r1 + r2 * r2 + r3 * r3;
#pragma unroll
    for (int o = 1; o < 64; o <<= 1) { s += __shfl_xor(s, o, 64); ss += __shfl_xor(ss, o, 64); }
    int w = t >> 6;
    if ((t & 63) == 0) { red[w] = s; red[4 + w] = ss; }
    __syncthreads();
    s = red[0] + red[1] + red[2] + red[3];
    ss = red[4] + red[5] + red[6] + red[7];
    float mu = s * (1.f / 1024.f);
    float var = ss * (1.f / 1024.f) - mu * mu;
    float inv = rsqrtf(var + 1e-12f);
    const float4 g4 = ((const float4*)gamma)[t];
    const float4 b4 = ((const float4*)beta)[t];
    float4 o4;
    o4.x = (r0 - mu) * inv * g4.x + b4.x;
    o4.y = (r1 - mu) * inv * g4.y + b4.y;
    o4.z = (r2 - mu) * inv * g4.z + b4.z;
    o4.w = (r3 - mu) * inv * g4.w + b4.w;
    ((float4*)(out + (size_t)row * 1024))[t] = o4;
}

extern "C" void kernel_launch(void* const* d_in, const int* in_sizes, int n_in,
                              void* d_out, int out_size, void* d_ws, size_t ws_size,
                              hipStream_t stream) {
    const float* x     = (const float*)d_in[0];
    const float* mask  = (const float*)d_in[1];
    const float* Wq    = (const float*)d_in[2];
    const float* bq    = (const float*)d_in[3];
    const float* Wk    = (const float*)d_in[4];
    const float* bk    = (const float*)d_in[5];
    const float* Wv    = (const float*)d_in[6];
    const float* bv    = (const float*)d_in[7];
    const float* Wo    = (const float*)d_in[8];
    const float* bo    = (const float*)d_in[9];
    const float* gamma = (const float*)d_in[10];
    const float* beta  = (const float*)d_in[11];
    float* out = (float*)d_out;

    char* ws = (char*)d_ws;
    ushortT* Xb  = (ushortT*)(ws);
    ushortT* Wqb = (ushortT*)(ws + (16u << 20));
    ushortT* Wkb = (ushortT*)(ws + (18u << 20));
    ushortT* Wvb = (ushortT*)(ws + (20u << 20));
    ushortT* Wob = (ushortT*)(ws + (22u << 20));
    ushortT* Qb  = (ushortT*)(ws + (24u << 20));
    ushortT* Kb  = (ushortT*)(ws + (40u << 20));
    ushortT* Vb  = (ushortT*)(ws + (56u << 20));  // V^T [bh][d][s]
    ushortT* Cb  = (ushortT*)(ws);                // ctx reuses Xb
    float*   Pj  = (float*)(ws + (24u << 20));    // fp32 proj reuses Q/K

    cvt_x<<<8192, 256, 0, stream>>>(x, Xb, 2097152);
    cvt_w<<<dim3(1024, 4), 256, 0, stream>>>(Wq, Wk, Wv, Wo, Wqb, Wkb, Wvb, Wob, 262144);
    qkv_gemm<<<1536, 256, 0, stream>>>(Xb, Wqb, Wkb, Wvb, bq, bk, bv, Qb, Kb, Vb);
    attn_kernel<<<1024, 256, 0, stream>>>(Qb, Kb, Vb, mask, Cb);
    oproj_gemm<<<512, 256, 0, stream>>>(Cb, Wob, bo, Pj);
    ln_kernel<<<8192, 256, 0, stream>>>(Pj, x, gamma, beta, out);
}

// Round 7
// 294.145 us; speedup vs baseline: 1.4242x; 1.0909x over previous
//
#include <hip/hip_runtime.h>

#define NHh 16

typedef unsigned short ushortT;
typedef __attribute__((ext_vector_type(8))) short short8;
typedef __attribute__((ext_vector_type(4))) float floatx4;

__device__ __forceinline__ ushortT f2bf(float x) {
    union { float f; unsigned int u; } cv; cv.f = x;
    unsigned int u = cv.u;
    unsigned int r = u + 0x7fffu + ((u >> 16) & 1u);
    return (ushortT)(r >> 16);
}

// truncating pack of two fp32 -> packed bf16x2 (cheap; used for P which is in [0,1])
__device__ __forceinline__ unsigned pack2_trunc(float a, float b) {
    union { float f; unsigned u; } ua, ub;
    ua.f = a; ub.f = b;
    return (ub.u & 0xffff0000u) | (ua.u >> 16);
}

__device__ __forceinline__ void gload_lds16(const ushortT* g, ushortT* l) {
    __builtin_amdgcn_global_load_lds(
        (const __attribute__((address_space(1))) void*)g,
        (__attribute__((address_space(3))) void*)l, 16, 0, 0);
}

// ---------------- fp32 -> bf16 converters ----------------
__global__ __launch_bounds__(256) void cvt_x(const float* __restrict__ in,
                                             ushortT* __restrict__ out, int n4) {
    int i = blockIdx.x * 256 + threadIdx.x;
    if (i >= n4) return;
    float4 f = ((const float4*)in)[i];
    uint2 o;
    o.x = (unsigned)f2bf(f.x) | ((unsigned)f2bf(f.y) << 16);
    o.y = (unsigned)f2bf(f.z) | ((unsigned)f2bf(f.w) << 16);
    ((uint2*)out)[i] = o;
}

__global__ __launch_bounds__(256) void cvt_w(const float* __restrict__ W0, const float* __restrict__ W1,
                                             const float* __restrict__ W2, const float* __restrict__ W3,
                                             ushortT* __restrict__ o0, ushortT* __restrict__ o1,
                                             ushortT* __restrict__ o2, ushortT* __restrict__ o3, int n4) {
    int z = blockIdx.y;
    const float* in = (z == 0) ? W0 : (z == 1) ? W1 : (z == 2) ? W2 : W3;
    ushortT* out = (z == 0) ? o0 : (z == 1) ? o1 : (z == 2) ? o2 : o3;
    int i = blockIdx.x * 256 + threadIdx.x;
    if (i >= n4) return;
    float4 f = ((const float4*)in)[i];
    uint2 o;
    o.x = (unsigned)f2bf(f.x) | ((unsigned)f2bf(f.y) << 16);
    o.y = (unsigned)f2bf(f.z) | ((unsigned)f2bf(f.w) << 16);
    ((uint2*)out)[i] = o;
}

// ---------------- QKV GEMM ----------------
// 1-D grid, 1536 blocks: m = l%64 (XCD = m%8 -> A-tile L2-resident), r=l/64, z=r/8, n=r%8.
// z=0/1 (Q,K): out[token,dim] -> [bh][s][d]; z=2 (V): swapped operands -> V^T [bh][d][s].
__global__ __launch_bounds__(256) void qkv_gemm(const ushortT* __restrict__ X,
        const ushortT* __restrict__ W0, const ushortT* __restrict__ W1, const ushortT* __restrict__ W2,
        const float* __restrict__ b0, const float* __restrict__ b1, const float* __restrict__ b2,
        ushortT* __restrict__ Qo, ushortT* __restrict__ Ko, ushortT* __restrict__ Vo) {
    __shared__ ushortT As[128 * 32];
    __shared__ ushortT Bs[128 * 32];
    const int l = blockIdx.x;
    const int mt = l & 63;
    const int r = l >> 6;
    const int z = r >> 3;
    const int nt = r & 7;
    const int tid = threadIdx.x;
    const int lane = tid & 63;
    const int w = tid >> 6;
    const int qd = lane >> 4;
    const int ln = lane & 15;
    const ushortT* Wt = (z == 0) ? W0 : (z == 1) ? W1 : W2;
    const float* bias = (z == 0) ? b0 : (z == 1) ? b1 : b2;
    const int RM = (w >> 1) * 64;
    const int RN = (w & 1) * 64;

    const ushortT* Ap;
    const ushortT* Bp;
    int arow0, brow0;
    if (z == 2) { Ap = Wt; arow0 = nt * 128; Bp = X;  brow0 = mt * 128; }
    else        { Ap = X;  arow0 = mt * 128; Bp = Wt; brow0 = nt * 128; }

    floatx4 acc[4][4];
#pragma unroll
    for (int i = 0; i < 4; i++)
#pragma unroll
        for (int j = 0; j < 4; j++) acc[i][j] = (floatx4){0.f, 0.f, 0.f, 0.f};

    const int c0 = tid, c1 = tid + 256;
    for (int k0 = 0; k0 < 1024; k0 += 32) {
        gload_lds16(Ap + (size_t)(arow0 + (c0 >> 2)) * 1024 + k0 + (c0 & 3) * 8, As + c0 * 8);
        gload_lds16(Ap + (size_t)(arow0 + (c1 >> 2)) * 1024 + k0 + (c1 & 3) * 8, As + c1 * 8);
        gload_lds16(Bp + (size_t)(brow0 + (c0 >> 2)) * 1024 + k0 + (c0 & 3) * 8, Bs + c0 * 8);
        gload_lds16(Bp + (size_t)(brow0 + (c1 >> 2)) * 1024 + k0 + (c1 & 3) * 8, Bs + c1 * 8);
        __syncthreads();
        short8 af[4], bf8[4];
#pragma unroll
        for (int i = 0; i < 4; i++) af[i] = *(const short8*)&As[(RM + i * 16 + ln) * 32 + qd * 8];
#pragma unroll
        for (int j = 0; j < 4; j++) bf8[j] = *(const short8*)&Bs[(RN + j * 16 + ln) * 32 + qd * 8];
#pragma unroll
        for (int i = 0; i < 4; i++)
#pragma unroll
            for (int j = 0; j < 4; j++)
                acc[i][j] = __builtin_amdgcn_mfma_f32_16x16x32_bf16(af[i], bf8[j], acc[i][j], 0, 0, 0);
        __syncthreads();
    }

    if (z == 2) {
        floatx4 bias4[4];
#pragma unroll
        for (int i = 0; i < 4; i++) bias4[i] = *(const floatx4*)(bias + arow0 + RM + i * 16 + qd * 4);
#pragma unroll
        for (int j = 0; j < 4; j++) {
            int m = brow0 + RN + j * 16 + ln;   // token
            int bb = m >> 10, s = m & 1023;
#pragma unroll
            for (int i = 0; i < 4; i++) {
#pragma unroll
                for (int r2 = 0; r2 < 4; r2++) {
                    int a = arow0 + RM + i * 16 + qd * 4 + r2;  // dim
                    int hh = a >> 6, dd = a & 63;
                    float v = acc[i][j][r2] + bias4[i][r2];
                    Vo[((size_t)(bb * NHh + hh) * 64 + dd) * 1024 + s] = f2bf(v);
                }
            }
        }
    } else {
        ushortT* Out = (z == 0) ? Qo : Ko;
#pragma unroll
        for (int j = 0; j < 4; j++) {
            int n = brow0 + RN + j * 16 + ln;   // dim
            float bb = bias[n];
            int h = n >> 6, d = n & 63;
#pragma unroll
            for (int i = 0; i < 4; i++) {
#pragma unroll
                for (int r2 = 0; r2 < 4; r2++) {
                    int m = arow0 + RM + i * 16 + qd * 4 + r2;  // token
                    int b = m >> 10, s = m & 1023;
                    float v = acc[i][j][r2] + bb;
                    Out[(size_t)((b * NHh + h) * 1024 + s) * 64 + d] = f2bf(v);
                }
            }
        }
    }
}

// ---------------- out-proj GEMM (fp32 out), 1-D grid 512: m=l%64, n=l/64 ----------------
__global__ __launch_bounds__(256) void oproj_gemm(const ushortT* __restrict__ A,
        const ushortT* __restrict__ Wt, const float* __restrict__ bias, float* __restrict__ Pj) {
    __shared__ ushortT As[128 * 32];
    __shared__ ushortT Bs[128 * 32];
    const int l = blockIdx.x;
    const int m0 = (l & 63) * 128;
    const int n0 = (l >> 6) * 128;
    const int tid = threadIdx.x;
    const int lane = tid & 63;
    const int w = tid >> 6;
    const int qd = lane >> 4;
    const int ln = lane & 15;
    const int RM = (w >> 1) * 64;
    const int RN = (w & 1) * 64;

    floatx4 acc[4][4];
#pragma unroll
    for (int i = 0; i < 4; i++)
#pragma unroll
        for (int j = 0; j < 4; j++) acc[i][j] = (floatx4){0.f, 0.f, 0.f, 0.f};

    const int c0 = tid, c1 = tid + 256;
    for (int k0 = 0; k0 < 1024; k0 += 32) {
        gload_lds16(A + (size_t)(m0 + (c0 >> 2)) * 1024 + k0 + (c0 & 3) * 8, As + c0 * 8);
        gload_lds16(A + (size_t)(m0 + (c1 >> 2)) * 1024 + k0 + (c1 & 3) * 8, As + c1 * 8);
        gload_lds16(Wt + (size_t)(n0 + (c0 >> 2)) * 1024 + k0 + (c0 & 3) * 8, Bs + c0 * 8);
        gload_lds16(Wt + (size_t)(n0 + (c1 >> 2)) * 1024 + k0 + (c1 & 3) * 8, Bs + c1 * 8);
        __syncthreads();
        short8 af[4], bf8[4];
#pragma unroll
        for (int i = 0; i < 4; i++) af[i] = *(const short8*)&As[(RM + i * 16 + ln) * 32 + qd * 8];
#pragma unroll
        for (int j = 0; j < 4; j++) bf8[j] = *(const short8*)&Bs[(RN + j * 16 + ln) * 32 + qd * 8];
#pragma unroll
        for (int i = 0; i < 4; i++)
#pragma unroll
            for (int j = 0; j < 4; j++)
                acc[i][j] = __builtin_amdgcn_mfma_f32_16x16x32_bf16(af[i], bf8[j], acc[i][j], 0, 0, 0);
        __syncthreads();
    }

#pragma unroll
    for (int j = 0; j < 4; j++) {
        int n = n0 + RN + j * 16 + ln;
        float bb = bias[n];
#pragma unroll
        for (int i = 0; i < 4; i++) {
#pragma unroll
            for (int r2 = 0; r2 < 4; r2++) {
                int m = m0 + RM + i * 16 + qd * 4 + r2;
                Pj[(size_t)m * 1024 + n] = acc[i][j][r2] + bb;
            }
        }
    }
}

// ---------------- flash attention: 256-q tile, LDS-staged K/V (XOR-swizzled) ----------------
// 1-D grid 512: bh = l%128 (XCD = bh%8 -> K/V L2-resident), qb = l/128 (0..3).
// Each block: 256 q rows; each wave owns 64 q. Grid = exactly 2 blocks/CU (no tail);
// each staged 32KB K/V tile feeds 2x the MFMA of the 128-q version.
// Registers ~190 live -> __launch_bounds__(256,2) (VGPR cap 256, no spill).
__global__ __launch_bounds__(256, 2) void attn_kernel(const ushortT* __restrict__ Q,
        const ushortT* __restrict__ K, const ushortT* __restrict__ Vg_t,
        const float* __restrict__ mask, ushortT* __restrict__ ctx) {
    __shared__ __align__(16) ushortT Ks[128 * 64];      // 16 KB
    __shared__ __align__(16) ushortT Vt[64 * 128];      // 16 KB
    __shared__ __align__(16) ushortT Ps[4][64 * 72];    // 36 KB, per-wave [64 q][64 s + pad]

    const int tid = threadIdx.x;
    const int lane = tid & 63;
    const int w = tid >> 6;
    const int qd = lane >> 4;
    const int ln = lane & 15;
    const int l = blockIdx.x;
    const int bh = l & 127;
    const int b = bh >> 4;
    const int h = bh & 15;
    const int qb = l >> 7;

    const ushortT* Qg = Q + (size_t)bh * 65536;
    const ushortT* Kg = K + (size_t)bh * 65536;
    const ushortT* Vg = Vg_t + (size_t)bh * 65536;
    const float* mrow = mask + b * 1024;
    const float LOG2E = 1.4426950408889634f;
    const float SCL = 0.125f * 1.4426950408889634f;   // fold 1/sqrt(64) and log2e

    // resident Q B-fragments: q = qb*256 + w*64 + nj*16 + ln
    short8 qf[4][2];
#pragma unroll
    for (int nj = 0; nj < 4; nj++)
#pragma unroll
        for (int ks = 0; ks < 2; ks++)
            qf[nj][ks] = *(const short8*)(Qg + (size_t)(qb * 256 + w * 64 + nj * 16 + ln) * 64 + ks * 32 + qd * 8);

    float lst[4] = {0.f, 0.f, 0.f, 0.f};
    floatx4 accO[4][4];
#pragma unroll
    for (int i = 0; i < 4; i++)
#pragma unroll
        for (int j = 0; j < 4; j++) accO[i][j] = (floatx4){0.f, 0.f, 0.f, 0.f};

    // staging lane geometry
    const int ksr = lane >> 3;          // K: s-subrow within 8-row group
    const int kc  = lane & 7;           // K: chunk index (8 x 16B per 128B row)
    const int vdr = lane >> 4;          // V: d-subrow within 4-row group
    const int vcc = lane & 15;          // V: chunk index (16 x 16B per 256B row)

    for (int kt = 0; kt < 8; ++kt) {
        __syncthreads();   // all waves done reading Ks/Vt of kt-1

        // stage K tile [128 s][64 d], chunk g of row s at slot g^(s&7)
#pragma unroll
        for (int ii = 0; ii < 4; ii++) {
            int i = w * 4 + ii;
            int srow = i * 8 + ksr;
            gload_lds16(Kg + (size_t)(kt * 128 + srow) * 64 + (kc ^ ksr) * 8,
                        Ks + i * 512 + lane * 8);
        }
        // stage V^T tile [64 d][128 s], chunk g of row d at slot g^(d&15)
#pragma unroll
        for (int ii = 0; ii < 4; ii++) {
            int i = w * 4 + ii;
            int d = i * 4 + vdr;
            gload_lds16(Vg + (size_t)d * 1024 + kt * 128 + (vcc ^ (d & 15)) * 8,
                        Vt + i * 512 + lane * 8);
        }

        __syncthreads();   // tiles ready

#pragma unroll
        for (int h2 = 0; h2 < 2; ++h2) {
            const int s0g = kt * 128 + h2 * 64;

            // ---- S^T in nj-pairs (caps sv live regs at 32) ----
#pragma unroll
            for (int njp = 0; njp < 2; ++njp) {
                floatx4 sv[4][2];
#pragma unroll
                for (int mi = 0; mi < 4; mi++)
#pragma unroll
                    for (int j = 0; j < 2; j++) sv[mi][j] = (floatx4){0.f, 0.f, 0.f, 0.f};
#pragma unroll
                for (int ks = 0; ks < 2; ks++) {
                    short8 af[4];
#pragma unroll
                    for (int mi = 0; mi < 4; mi++)
                        af[mi] = *(const short8*)&Ks[(h2 * 64 + mi * 16 + ln) * 64 +
                                                     (((ks * 4 + qd) ^ (ln & 7)) * 8)];
#pragma unroll
                    for (int mi = 0; mi < 4; mi++)
#pragma unroll
                        for (int j = 0; j < 2; j++)
                            sv[mi][j] = __builtin_amdgcn_mfma_f32_16x16x32_bf16(af[mi], qf[njp * 2 + j][ks], sv[mi][j], 0, 0, 0);
                }

                // softmax-lite + per-wave Ps write
                float rs0 = 0.f, rs1 = 0.f;
#pragma unroll
                for (int mi = 0; mi < 4; mi++) {
                    floatx4 m4 = *(const floatx4*)(mrow + s0g + mi * 16 + qd * 4);
                    float p00 = __builtin_amdgcn_exp2f(sv[mi][0][0] * SCL + m4[0] * LOG2E);
                    float p01 = __builtin_amdgcn_exp2f(sv[mi][0][1] * SCL + m4[1] * LOG2E);
                    float p02 = __builtin_amdgcn_exp2f(sv[mi][0][2] * SCL + m4[2] * LOG2E);
                    float p03 = __builtin_amdgcn_exp2f(sv[mi][0][3] * SCL + m4[3] * LOG2E);
                    float p10 = __builtin_amdgcn_exp2f(sv[mi][1][0] * SCL + m4[0] * LOG2E);
                    float p11 = __builtin_amdgcn_exp2f(sv[mi][1][1] * SCL + m4[1] * LOG2E);
                    float p12 = __builtin_amdgcn_exp2f(sv[mi][1][2] * SCL + m4[2] * LOG2E);
                    float p13 = __builtin_amdgcn_exp2f(sv[mi][1][3] * SCL + m4[3] * LOG2E);
                    rs0 += (p00 + p01) + (p02 + p03);
                    rs1 += (p10 + p11) + (p12 + p13);
                    uint2 w0, w1;
                    w0.x = pack2_trunc(p00, p01); w0.y = pack2_trunc(p02, p03);
                    w1.x = pack2_trunc(p10, p11); w1.y = pack2_trunc(p12, p13);
                    *(uint2*)&Ps[w][(njp * 32 + ln) * 72 + mi * 16 + qd * 4] = w0;
                    *(uint2*)&Ps[w][(njp * 32 + 16 + ln) * 72 + mi * 16 + qd * 4] = w1;
                }
                rs0 += __shfl_xor(rs0, 16, 64); rs0 += __shfl_xor(rs0, 32, 64);
                rs1 += __shfl_xor(rs1, 16, 64); rs1 += __shfl_xor(rs1, 32, 64);
                lst[njp * 2 + 0] += rs0;
                lst[njp * 2 + 1] += rs1;
            }

            // ---- PV: A = P (per-wave LDS, 64 q rows), B = V^T (LDS, swizzled) ----
#pragma unroll
            for (int ks2 = 0; ks2 < 2; ks2++) {
                short8 ap[4], bv[4];
#pragma unroll
                for (int i = 0; i < 4; i++)
                    ap[i] = *(const short8*)&Ps[w][(i * 16 + ln) * 72 + ks2 * 32 + qd * 8];
#pragma unroll
                for (int j = 0; j < 4; j++)
                    bv[j] = *(const short8*)&Vt[(j * 16 + ln) * 128 +
                                                (((h2 * 8 + ks2 * 4 + qd) ^ ln) * 8)];
#pragma unroll
                for (int i = 0; i < 4; i++)
#pragma unroll
                    for (int j = 0; j < 4; j++)
                        accO[i][j] = __builtin_amdgcn_mfma_f32_16x16x32_bf16(ap[i], bv[j], accO[i][j], 0, 0, 0);
            }
        }
    }

    // epilogue: divide by l (lane transpose once) and store ctx [b][s=q][h*64+d]
#pragma unroll
    for (int i = 0; i < 4; i++) {
#pragma unroll
        for (int r = 0; r < 4; r++) {
            float lv = __shfl(lst[i], qd * 4 + r, 64);
            float linv = 1.f / lv;
            int q = qb * 256 + w * 64 + i * 16 + qd * 4 + r;
#pragma unroll
            for (int j = 0; j < 4; j++) {
                int d = j * 16 + ln;
                ctx[((size_t)(b * 1024 + q)) * 1024 + h * 64 + d] = f2bf(accO[i][j][r] * linv);
            }
        }
    }
}

// ---------------- residual + LayerNorm ----------------
__global__ __launch_bounds__(256) void ln_kernel(const float* __restrict__ Pj, const float* __restrict__ X,
        const float* __restrict__ gamma, const float* __restrict__ beta, float* __restrict__ out) {
    __shared__ float red[8];
    int row = blockIdx.x;
    int t = threadIdx.x;
    const float4 p4 = ((const float4*)(Pj + (size_t)row * 1024))[t];
    const float4 x4 = ((const float4*)(X + (size_t)row * 1024))[t];
    float r0 = p4.x + x4.x, r1 = p4.y + x4.y, r2 = p4.z + x4.z, r3 = p4.w + x4.w;
    float s = r0 + r1 + r2 + r3;
    float ss = r0 * r0 + r1 * r1 + r2 * r2 + r3 * r3;
#pragma unroll
    for (int o = 1; o < 64; o <<= 1) { s += __shfl_xor(s, o, 64); ss += __shfl_xor(ss, o, 64); }
    int w = t >> 6;
    if ((t & 63) == 0) { red[w] = s; red[4 + w] = ss; }
    __syncthreads();
    s = red[0] + red[1] + red[2] + red[3];
    ss = red[4] + red[5] + red[6] + red[7];
    float mu = s * (1.f / 1024.f);
    float var = ss * (1.f / 1024.f) - mu * mu;
    float inv = rsqrtf(var + 1e-12f);
    const float4 g4 = ((const float4*)gamma)[t];
    const float4 b4 = ((const float4*)beta)[t];
    float4 o4;
    o4.x = (r0 - mu) * inv * g4.x + b4.x;
    o4.y = (r1 - mu) * inv * g4.y + b4.y;
    o4.z = (r2 - mu) * inv * g4.z + b4.z;
    o4.w = (r3 - mu) * inv * g4.w + b4.w;
    ((float4*)(out + (size_t)row * 1024))[t] = o4;
}

extern "C" void kernel_launch(void* const* d_in, const int* in_sizes, int n_in,
                              void* d_out, int out_size, void* d_ws, size_t ws_size,
                              hipStream_t stream) {
    const float* x     = (const float*)d_in[0];
    const float* mask  = (const float*)d_in[1];
    const float* Wq    = (const float*)d_in[2];
    const float* bq    = (const float*)d_in[3];
    const float* Wk    = (const float*)d_in[4];
    const float* bk    = (const float*)d_in[5];
    const float* Wv    = (const float*)d_in[6];
    const float* bv    = (const float*)d_in[7];
    const float* Wo    = (const float*)d_in[8];
    const float* bo    = (const float*)d_in[9];
    const float* gamma = (const float*)d_in[10];
    const float* beta  = (const float*)d_in[11];
    float* out = (float*)d_out;

    char* ws = (char*)d_ws;
    ushortT* Xb  = (ushortT*)(ws);
    ushortT* Wqb = (ushortT*)(ws + (16u << 20));
    ushortT* Wkb = (ushortT*)(ws + (18u << 20));
    ushortT* Wvb = (ushortT*)(ws + (20u << 20));
    ushortT* Wob = (ushortT*)(ws + (22u << 20));
    ushortT* Qb  = (ushortT*)(ws + (24u << 20));
    ushortT* Kb  = (ushortT*)(ws + (40u << 20));
    ushortT* Vb  = (ushortT*)(ws + (56u << 20));  // V^T [bh][d][s]
    ushortT* Cb  = (ushortT*)(ws);                // ctx reuses Xb
    float*   Pj  = (float*)(ws + (24u << 20));    // fp32 proj reuses Q/K

    cvt_x<<<8192, 256, 0, stream>>>(x, Xb, 2097152);
    cvt_w<<<dim3(1024, 4), 256, 0, stream>>>(Wq, Wk, Wv, Wo, Wqb, Wkb, Wvb, Wob, 262144);
    qkv_gemm<<<1536, 256, 0, stream>>>(Xb, Wqb, Wkb, Wvb, bq, bk, bv, Qb, Kb, Vb);
    attn_kernel<<<512, 256, 0, stream>>>(Qb, Kb, Vb, mask, Cb);
    oproj_gemm<<<512, 256, 0, stream>>>(Cb, Wob, bo, Pj);
    ln_kernel<<<8192, 256, 0, stream>>>(Pj, x, gamma, beta, out);
}